// Round 7
// baseline (1693.885 us; speedup 1.0000x reference)
//
#include <hip/hip_runtime.h>
#include <math.h>

typedef unsigned short u16;
typedef short bf16x8 __attribute__((ext_vector_type(8)));
typedef float f32x4 __attribute__((ext_vector_type(4)));

__device__ __forceinline__ u16 f2b(float x) {
    unsigned u = __builtin_bit_cast(unsigned, x);
    unsigned r = u + 0x7fffu + ((u >> 16) & 1u);
    return (u16)(r >> 16);
}
__device__ __forceinline__ float b2f(u16 v) {
    return __builtin_bit_cast(float, (unsigned)v << 16);
}
__device__ __forceinline__ void gl_lds16(const u16* g, u16* l) {
    __builtin_amdgcn_global_load_lds(
        (const __attribute__((address_space(1))) unsigned int*)g,
        (__attribute__((address_space(3))) unsigned int*)l, 16, 0, 0);
}
__device__ __forceinline__ float wred_sum(float v) {
#pragma unroll
    for (int o = 32; o > 0; o >>= 1) v += __shfl_down(v, o, 64);
    return v;
}
__device__ __forceinline__ float wred_max(float v) {
#pragma unroll
    for (int o = 32; o > 0; o >>= 1) v = fmaxf(v, __shfl_down(v, o, 64));
    return v;
}

// ================= bf16 MFMA GEMM (NT): C[M][N] = A[M][K] @ B[N][K]^T ==========
// LDS chunk layout [4 ksegs][16 rows][8]; conflict-free ds_read_b128.
// MODE: 0 plain fp32 C; 1 bias+relu; 2 C += acc + bias;
//       4 qkv-split bf16 via LDS-staged COALESCED stores (q*0.125 -> Q [h][n][64],
//         k -> Kb [h][n][64], v -> V^T [d_global][n])  -- avoids sub-line RMW.
struct GP {
    const u16* A; const u16* B; float* C;
    u16* Q; u16* Kb; u16* V;
    const float* bias;
    long sA, sB, sC;
    int K, ldc, tilesN;
};

template <int BM, int BN, int MODE>
__global__ __launch_bounds__(256) void mgemm(GP p) {
    constexpr int WN = BN / 64;
    constexpr int LA = BM / 64;
    constexpr int LB = BN / 64;
    constexpr int SM = (MODE == 4) ? (BM * 136) : (BM * 32 + BN * 32);
    __shared__ u16 smem[SM] __attribute__((aligned(16)));
    u16* As = smem;
    u16* Bs = smem + BM * 32;

    int tid = threadIdx.x, lane = tid & 63, wave = tid >> 6;
    int wm = wave / WN, wn = wave % WN;
    int tm = blockIdx.x / p.tilesN, tn = blockIdx.x % p.tilesN;
    int batch = blockIdx.y;
    int m0 = tm * BM, n0 = tn * BN;
    const u16* A = p.A + (long)batch * p.sA;
    const u16* B = p.B + (long)batch * p.sB;

    f32x4 acc[4][4];
#pragma unroll
    for (int i = 0; i < 4; i++)
#pragma unroll
        for (int j = 0; j < 4; j++) acc[i][j] = (f32x4){0.f, 0.f, 0.f, 0.f};

    int lr = lane & 15;
    int lcb = (lane >> 4) << 3;
    int quad = lane >> 4, cn = lane & 15;
    for (int k0 = 0; k0 < p.K; k0 += 32) {
#pragma unroll
        for (int i = 0; i < LA; i++) {
            int chunk = wave * LA + i;
            gl_lds16(A + (long)(m0 + chunk * 16 + lr) * p.K + k0 + lcb,
                     As + chunk * 512 + lane * 8);
        }
#pragma unroll
        for (int i = 0; i < LB; i++) {
            int chunk = wave * LB + i;
            gl_lds16(B + (long)(n0 + chunk * 16 + lr) * p.K + k0 + lcb,
                     Bs + chunk * 512 + lane * 8);
        }
        __syncthreads();
        bf16x8 af[4], bfv[4];
#pragma unroll
        for (int mi = 0; mi < 4; mi++)
            af[mi] = *(const bf16x8*)(As + (wm * 4 + mi) * 512 + quad * 128 + cn * 8);
#pragma unroll
        for (int ni = 0; ni < 4; ni++)
            bfv[ni] = *(const bf16x8*)(Bs + (wn * 4 + ni) * 512 + quad * 128 + cn * 8);
#pragma unroll
        for (int mi = 0; mi < 4; mi++)
#pragma unroll
            for (int ni = 0; ni < 4; ni++)
                acc[mi][ni] = __builtin_amdgcn_mfma_f32_16x16x32_bf16(
                    af[mi], bfv[ni], acc[mi][ni], 0, 0, 0);
        __syncthreads();
    }

    if constexpr (MODE == 4) {
        // stage bf16 C-tile in LDS (stride 136 u16 to avoid quad conflicts)
        float qs = (tn < 4) ? 0.125f : 1.f;
#pragma unroll
        for (int mi = 0; mi < 4; mi++)
#pragma unroll
            for (int ni = 0; ni < 4; ni++)
#pragma unroll
                for (int r = 0; r < 4; r++) {
                    int row = wm * 64 + mi * 16 + quad * 4 + r;
                    int col = wn * 64 + ni * 16 + cn;
                    smem[row * 136 + col] = f2b(acc[mi][ni][r] * qs);
                }
        __syncthreads();
        if (tn < 8) {
            // Q or K region: coalesced 16B/lane stores, full 128B per row
            u16* dst0 = (tn < 4) ? p.Q : p.Kb;
            int cbase = (tn & 3) * 128;
#pragma unroll
            for (int pass = 0; pass < 8; pass++) {
                int row = pass * 16 + (tid >> 4);
                int col = (tid & 15) * 8;
                int gh = (cbase + col) >> 6, gd = (cbase + col) & 63;
                uint4 v = *(const uint4*)(smem + row * 136 + col);
                *(uint4*)(dst0 + ((long)gh * 16384 + m0 + row) * 64 + gd) = v;
            }
        } else {
            // V region: transposed store into VT[d_global][n], 128B/lane contiguous
            int c = tid & 127, rb = tid >> 7;
            int vd = (tn - 8) * 128 + c;
            u16 tmp[64];
#pragma unroll
            for (int j = 0; j < 64; j++) tmp[j] = smem[(rb * 64 + j) * 136 + c];
            uint4* dst = (uint4*)(p.V + (long)vd * 16384 + m0 + rb * 64);
#pragma unroll
            for (int q8 = 0; q8 < 8; q8++) dst[q8] = *(const uint4*)(tmp + q8 * 8);
        }
    } else {
        float* C = p.C + (long)batch * p.sC;
#pragma unroll
        for (int mi = 0; mi < 4; mi++) {
#pragma unroll
            for (int ni = 0; ni < 4; ni++) {
#pragma unroll
                for (int r = 0; r < 4; r++) {
                    int row = m0 + wm * 64 + mi * 16 + quad * 4 + r;
                    int col = n0 + wn * 64 + ni * 16 + cn;
                    float v = acc[mi][ni][r];
                    if (MODE == 0) {
                        C[(long)row * p.ldc + col] = v;
                    } else if (MODE == 1) {
                        C[(long)row * p.ldc + col] = fmaxf(v + p.bias[col], 0.f);
                    } else if (MODE == 2) {
                        C[(long)row * p.ldc + col] += v + p.bias[col];
                    }
                }
            }
        }
    }
}

template <int BM, int BN, int MODE>
static void launch_mgemm(hipStream_t st, GP p, int M, int N, int batch) {
    p.tilesN = N / BN;
    dim3 grid((M / BM) * (N / BN), batch);
    mgemm<BM, BN, MODE><<<grid, 256, 0, st>>>(p);
}

// ================= fused sim3 flash (64 splits x 8 heads) ======================
// Per (head,split): 256 keys in 4 chunks of 64. Partials: m[256],l[256],O[256][64].
__global__ __launch_bounds__(256) void flash_a3v(
    const u16* __restrict__ QLb, const u16* __restrict__ Kb,
    const u16* __restrict__ VT, float* __restrict__ PART) {
    __shared__ u16 QLs[16384] __attribute__((aligned(16)));
    __shared__ u16 Ks[4096] __attribute__((aligned(16)));
    __shared__ u16 Vs[4096] __attribute__((aligned(16)));
    __shared__ u16 Ps[16384] __attribute__((aligned(16)));
    int tid = threadIdx.x, lane = tid & 63, w = tid >> 6;
    int head = blockIdx.y, split = blockIdx.x;
    const u16* QLh = QLb + (long)head * 256 * 64;
    const u16* Kh = Kb + ((long)head * 16384 + split * 256) * 64;
    const u16* Vh = VT + (long)head * 64 * 16384 + split * 256;
    int quad = lane >> 4, cn = lane & 15;
    int lr = lane & 15, lc = (lane >> 4) << 3;

    for (int c = w; c < 32; c += 4) {
        int rc = c >> 1, kc = c & 1;
        gl_lds16(QLh + (long)(rc * 16 + lr) * 64 + kc * 32 + lc, QLs + c * 512 + lane * 8);
    }
    __syncthreads();
    bf16x8 qf[4][2];
#pragma unroll
    for (int mi = 0; mi < 4; mi++)
#pragma unroll
        for (int kc = 0; kc < 2; kc++)
            qf[mi][kc] = *(const bf16x8*)(QLs + ((w * 4 + mi) * 2 + kc) * 512 +
                                          quad * 128 + cn * 8);

    f32x4 Oacc[4][4];
    float m_i[4][4], l_i[4][4];
#pragma unroll
    for (int i = 0; i < 4; i++)
#pragma unroll
        for (int j = 0; j < 4; j++) {
            Oacc[i][j] = (f32x4){0.f, 0.f, 0.f, 0.f};
            m_i[i][j] = -1e30f;
            l_i[i][j] = 0.f;
        }

    for (int t = 0; t < 4; t++) {
        for (int i = w; i < 8; i += 4) {
            int rc = i >> 1, kc = i & 1;
            gl_lds16(Kh + (long)(t * 64 + rc * 16 + lr) * 64 + kc * 32 + lc,
                     Ks + i * 512 + lane * 8);
        }
        for (int i = w; i < 8; i += 4) {
            int dc = i >> 1, kc = i & 1;
            gl_lds16(Vh + (long)(dc * 16 + lr) * 16384 + t * 64 + kc * 32 + lc,
                     Vs + i * 512 + lane * 8);
        }
        __syncthreads();
        f32x4 s[4][4];
#pragma unroll
        for (int i = 0; i < 4; i++)
#pragma unroll
            for (int j = 0; j < 4; j++) s[i][j] = (f32x4){0.f, 0.f, 0.f, 0.f};
#pragma unroll
        for (int kc = 0; kc < 2; kc++) {
            bf16x8 kf[4];
#pragma unroll
            for (int ni = 0; ni < 4; ni++)
                kf[ni] = *(const bf16x8*)(Ks + (ni * 2 + kc) * 512 + quad * 128 + cn * 8);
#pragma unroll
            for (int mi = 0; mi < 4; mi++)
#pragma unroll
                for (int ni = 0; ni < 4; ni++)
                    s[mi][ni] = __builtin_amdgcn_mfma_f32_16x16x32_bf16(
                        qf[mi][kc], kf[ni], s[mi][ni], 0, 0, 0);
        }
#pragma unroll
        for (int mi = 0; mi < 4; mi++) {
#pragma unroll
            for (int r = 0; r < 4; r++) {
                float mx = fmaxf(fmaxf(s[mi][0][r], s[mi][1][r]),
                                 fmaxf(s[mi][2][r], s[mi][3][r]));
                mx = fmaxf(mx, __shfl_xor(mx, 1));
                mx = fmaxf(mx, __shfl_xor(mx, 2));
                mx = fmaxf(mx, __shfl_xor(mx, 4));
                mx = fmaxf(mx, __shfl_xor(mx, 8));
                float mold = m_i[mi][r];
                float mnew = fmaxf(mold, mx);
                float alpha = __expf(mold - mnew);
                m_i[mi][r] = mnew;
                float sum = 0.f;
#pragma unroll
                for (int ni = 0; ni < 4; ni++) {
                    float e = __expf(s[mi][ni][r] - mnew);
                    sum += e;
                    int col = ni * 16 + cn;
                    Ps[w * 4096 + (mi * 2 + (col >> 5)) * 512 + ((col >> 3) & 3) * 128 +
                       (quad * 4 + r) * 8 + (col & 7)] = f2b(e);
                    Oacc[mi][ni][r] *= alpha;
                }
                sum += __shfl_xor(sum, 1);
                sum += __shfl_xor(sum, 2);
                sum += __shfl_xor(sum, 4);
                sum += __shfl_xor(sum, 8);
                l_i[mi][r] = l_i[mi][r] * alpha + sum;
            }
        }
        __syncthreads();
#pragma unroll
        for (int kc = 0; kc < 2; kc++) {
            bf16x8 vf[4], pf[4];
#pragma unroll
            for (int nd = 0; nd < 4; nd++)
                vf[nd] = *(const bf16x8*)(Vs + (nd * 2 + kc) * 512 + quad * 128 + cn * 8);
#pragma unroll
            for (int mi = 0; mi < 4; mi++)
                pf[mi] = *(const bf16x8*)(Ps + w * 4096 + (mi * 2 + kc) * 512 +
                                          quad * 128 + cn * 8);
#pragma unroll
            for (int mi = 0; mi < 4; mi++)
#pragma unroll
                for (int nd = 0; nd < 4; nd++)
                    Oacc[mi][nd] = __builtin_amdgcn_mfma_f32_16x16x32_bf16(
                        pf[mi], vf[nd], Oacc[mi][nd], 0, 0, 0);
        }
        __syncthreads();
    }
    float* base = PART + ((long)head * 64 + split) * 16896;
#pragma unroll
    for (int mi = 0; mi < 4; mi++) {
#pragma unroll
        for (int r = 0; r < 4; r++) {
            int row = w * 64 + mi * 16 + quad * 4 + r;
            if (cn == 0) {
                base[row] = m_i[mi][r];
                base[256 + row] = l_i[mi][r];
            }
#pragma unroll
            for (int ni = 0; ni < 4; ni++)
                base[512 + row * 64 + ni * 16 + cn] = Oacc[mi][ni][r];
        }
    }
}

__global__ __launch_bounds__(256) void a3v_combine(const float* __restrict__ PART,
                                                   float* __restrict__ O) {
    int head = blockIdx.x, rg = blockIdx.y;
    int t = threadIdx.x;
    int rl = t >> 6, d = t & 63;
    const float* ph = PART + (long)head * 64 * 16896;
    for (int rr = 0; rr < 16; rr++) {
        int row = rg * 64 + rr * 4 + rl;
        float m = -1e30f;
#pragma unroll 8
        for (int b = 0; b < 64; b++) m = fmaxf(m, ph[b * 16896 + row]);
        float l = 0.f, o = 0.f;
#pragma unroll 8
        for (int b = 0; b < 64; b++) {
            float a = __expf(ph[b * 16896 + row] - m);
            l += a * ph[b * 16896 + 256 + row];
            o += a * ph[b * 16896 + 512 + row * 64 + d];
        }
        O[((long)head * 256 + row) * 64 + d] = o / l;
    }
}

// ================= fused sim1 -> softmax -> @W2 -> +conv -> bf16 ==============
__global__ __launch_bounds__(256) void attn1_fused(
    const u16* __restrict__ Qb, const u16* __restrict__ KLb,
    const u16* __restrict__ W2T, const float* __restrict__ CONV,
    u16* __restrict__ OUTb) {
    __shared__ u16 lds[32768] __attribute__((aligned(16)));
    u16* Qs = lds;
    u16* KLs = lds + 4096;
    u16* Ps = lds;
    u16* W2s = lds + 16384;
    int tid = threadIdx.x, lane = tid & 63, w = tid >> 6;
    int head = blockIdx.y, n0 = blockIdx.x * 64;
    int quad = lane >> 4, cn = lane & 15;
    int lr = lane & 15, lc = (lane >> 4) << 3;
    const u16* Qh = Qb + (long)head * 16384 * 64;
    const u16* KLh = KLb + (long)head * 256 * 64;
    const u16* W2h = W2T + (long)head * 64 * 256;
#pragma unroll
    for (int c = 0; c < 2; c++)
        gl_lds16(Qh + (long)(n0 + w * 16 + lr) * 64 + c * 32 + lc,
                 Qs + c * 2048 + w * 512 + lane * 8);
#pragma unroll
    for (int c = 0; c < 2; c++)
#pragma unroll
        for (int rg = 0; rg < 4; rg++) {
            int chunk = rg * 4 + w;
            gl_lds16(KLh + (long)(chunk * 16 + lr) * 64 + c * 32 + lc,
                     KLs + c * 8192 + chunk * 512 + lane * 8);
        }
    __syncthreads();
    f32x4 acc[16];
#pragma unroll
    for (int i = 0; i < 16; i++) acc[i] = (f32x4){0.f, 0.f, 0.f, 0.f};
#pragma unroll
    for (int c = 0; c < 2; c++) {
        bf16x8 af = *(const bf16x8*)(Qs + c * 2048 + w * 512 + quad * 128 + cn * 8);
#pragma unroll
        for (int ni = 0; ni < 16; ni++) {
            bf16x8 bfv = *(const bf16x8*)(KLs + c * 8192 + ni * 512 + quad * 128 + cn * 8);
            acc[ni] = __builtin_amdgcn_mfma_f32_16x16x32_bf16(af, bfv, acc[ni], 0, 0, 0);
        }
    }
    __syncthreads();
#pragma unroll
    for (int r = 0; r < 4; r++) {
        float mx = -1e30f;
#pragma unroll
        for (int ni = 0; ni < 16; ni++) mx = fmaxf(mx, acc[ni][r]);
        mx = fmaxf(mx, __shfl_xor(mx, 1));
        mx = fmaxf(mx, __shfl_xor(mx, 2));
        mx = fmaxf(mx, __shfl_xor(mx, 4));
        mx = fmaxf(mx, __shfl_xor(mx, 8));
        float e[16];
        float s = 0.f;
#pragma unroll
        for (int ni = 0; ni < 16; ni++) {
            e[ni] = __expf(acc[ni][r] - mx);
            s += e[ni];
        }
        s += __shfl_xor(s, 1);
        s += __shfl_xor(s, 2);
        s += __shfl_xor(s, 4);
        s += __shfl_xor(s, 8);
        float inv = 1.f / s;
        int prow = w * 16 + quad * 4 + r;
#pragma unroll
        for (int ni = 0; ni < 16; ni++) {
            int k = ni * 16 + cn;
            Ps[(k >> 5) * 2048 + ((k >> 3) & 3) * 512 + prow * 8 + (k & 7)] =
                f2b(e[ni] * inv);
        }
    }
#pragma unroll
    for (int c = 0; c < 8; c++)
        gl_lds16(W2h + (long)(w * 16 + lr) * 256 + c * 32 + lc,
                 W2s + c * 2048 + w * 512 + lane * 8);
    __syncthreads();
    f32x4 acc2[4];
#pragma unroll
    for (int i = 0; i < 4; i++) acc2[i] = (f32x4){0.f, 0.f, 0.f, 0.f};
#pragma unroll
    for (int c = 0; c < 8; c++) {
        bf16x8 af = *(const bf16x8*)(Ps + c * 2048 + quad * 512 + (w * 16 + cn) * 8);
#pragma unroll
        for (int ni = 0; ni < 4; ni++) {
            bf16x8 bfv = *(const bf16x8*)(W2s + c * 2048 + ni * 512 + quad * 128 + cn * 8);
            acc2[ni] = __builtin_amdgcn_mfma_f32_16x16x32_bf16(af, bfv, acc2[ni], 0, 0, 0);
        }
    }
#pragma unroll
    for (int ni = 0; ni < 4; ni++)
#pragma unroll
        for (int r = 0; r < 4; r++) {
            int row = n0 + w * 16 + quad * 4 + r;
            long idx = (long)row * 512 + head * 64 + ni * 16 + cn;
            OUTb[idx] = f2b(CONV[idx] + acc2[ni][r]);
        }
}

// ================= fp32 tile GEMM (W2 = z @ a3v) ===============================
#define TILE 64
#define KT 16
#define LDP (TILE + 4)
__global__ __launch_bounds__(256) void gemm_kernel(
    const float* __restrict__ A, const float* __restrict__ B, float* __restrict__ C,
    int M, int N, int K, int lda, int ldb, int ldc,
    long sA, long sB, long sC, int tilesN) {
    int tm = blockIdx.x / tilesN, tn = blockIdx.x % tilesN;
    int batch = blockIdx.y;
    A += (long)batch * sA; B += (long)batch * sB; C += (long)batch * sC;
    int row0 = tm * TILE, col0 = tn * TILE;
    __shared__ float As[KT][LDP];
    __shared__ float Bs[KT][LDP];
    int t = threadIdx.x;
    int tx = t & 15, ty = t >> 4;
    float acc[4][4] = {{0.f}};
    int aRow = t >> 2, aK = (t & 3) << 2;
    int bN = t & 63, bK = (t >> 6) << 2;
    for (int k0 = 0; k0 < K; k0 += KT) {
        {
            int r = row0 + aRow;
            float4 av = make_float4(0.f, 0.f, 0.f, 0.f);
            if (r < M) av = *(const float4*)(A + (long)r * lda + k0 + aK);
            As[aK][aRow] = av.x; As[aK + 1][aRow] = av.y;
            As[aK + 2][aRow] = av.z; As[aK + 3][aRow] = av.w;
        }
        {
            const float* bp = B + (long)(k0 + bK) * ldb + col0 + bN;
            bool ok = col0 + bN < N;
#pragma unroll
            for (int j = 0; j < 4; j++) Bs[bK + j][bN] = ok ? bp[(long)j * ldb] : 0.f;
        }
        __syncthreads();
#pragma unroll
        for (int kk = 0; kk < KT; kk++) {
            float4 a = *(const float4*)&As[kk][ty << 2];
            float4 b = *(const float4*)&Bs[kk][tx << 2];
            acc[0][0] += a.x * b.x; acc[0][1] += a.x * b.y; acc[0][2] += a.x * b.z; acc[0][3] += a.x * b.w;
            acc[1][0] += a.y * b.x; acc[1][1] += a.y * b.y; acc[1][2] += a.y * b.z; acc[1][3] += a.y * b.w;
            acc[2][0] += a.z * b.x; acc[2][1] += a.z * b.y; acc[2][2] += a.z * b.z; acc[2][3] += a.z * b.w;
            acc[3][0] += a.w * b.x; acc[3][1] += a.w * b.y; acc[3][2] += a.w * b.z; acc[3][3] += a.w * b.w;
        }
        __syncthreads();
    }
#pragma unroll
    for (int i = 0; i < 4; i++) {
        int row = row0 + (ty << 2) + i;
        if (row >= M) continue;
        float* cp = C + (long)row * ldc + col0 + (tx << 2);
#pragma unroll
        for (int j = 0; j < 4; j++) {
            int col = col0 + (tx << 2) + j;
            if (col >= N) continue;
            cp[j] = acc[i][j];
        }
    }
}
static void gemm32(hipStream_t st, int M, int N, int K,
                   const float* A, int lda, long sA,
                   const float* B, int ldb, long sB,
                   float* C, int ldc, long sC, int batch) {
    int tilesM = (M + TILE - 1) / TILE, tilesN = (N + TILE - 1) / TILE;
    dim3 grid(tilesM * tilesN, batch);
    gemm_kernel<<<grid, 256, 0, st>>>(A, B, C, M, N, K, lda, ldb, ldc, sA, sB, sC, tilesN);
}

// ================= pinv fused chain (fp32; also emits z^T bf16) ================
__global__ __launch_bounds__(256) void pinv_chain(const float* __restrict__ xz,
                                                  const float* __restrict__ z,
                                                  float* __restrict__ zn,
                                                  u16* __restrict__ znT) {
    int h = blockIdx.y, c0 = blockIdx.x * 8;
    const float* X = xz + (long)h * 65536;
    const float* Z = z + (long)h * 65536;
    __shared__ float ta[256][8];
    __shared__ float tb[256][8];
    int t = threadIdx.x;
    const float4* X4 = (const float4*)(X + t * 256);
    const float4* Z4 = (const float4*)(Z + t * 256);
    float acc[8];
#pragma unroll
    for (int j = 0; j < 8; j++)
        ta[t][j] = ((t == c0 + j) ? 7.f : 0.f) - X[t * 256 + c0 + j];
    __syncthreads();
#pragma unroll
    for (int j = 0; j < 8; j++) acc[j] = 0.f;
    for (int k4 = 0; k4 < 64; k4++) {
        float4 xv = X4[k4];
#pragma unroll
        for (int j = 0; j < 8; j++)
            acc[j] += xv.x * ta[k4 * 4][j] + xv.y * ta[k4 * 4 + 1][j] +
                      xv.z * ta[k4 * 4 + 2][j] + xv.w * ta[k4 * 4 + 3][j];
    }
#pragma unroll
    for (int j = 0; j < 8; j++)
        tb[t][j] = ((t == c0 + j) ? 15.f : 0.f) - acc[j];
    __syncthreads();
#pragma unroll
    for (int j = 0; j < 8; j++) acc[j] = 0.f;
    for (int k4 = 0; k4 < 64; k4++) {
        float4 xv = X4[k4];
#pragma unroll
        for (int j = 0; j < 8; j++)
            acc[j] += xv.x * tb[k4 * 4][j] + xv.y * tb[k4 * 4 + 1][j] +
                      xv.z * tb[k4 * 4 + 2][j] + xv.w * tb[k4 * 4 + 3][j];
    }
    __syncthreads();
#pragma unroll
    for (int j = 0; j < 8; j++)
        ta[t][j] = ((t == c0 + j) ? 13.f : 0.f) - acc[j];
    __syncthreads();
#pragma unroll
    for (int j = 0; j < 8; j++) acc[j] = 0.f;
    for (int k4 = 0; k4 < 64; k4++) {
        float4 zv = Z4[k4];
#pragma unroll
        for (int j = 0; j < 8; j++)
            acc[j] += zv.x * ta[k4 * 4][j] + zv.y * ta[k4 * 4 + 1][j] +
                      zv.z * ta[k4 * 4 + 2][j] + zv.w * ta[k4 * 4 + 3][j];
    }
#pragma unroll
    for (int j = 0; j < 8; j++) {
        float v = 0.25f * acc[j];
        zn[(long)h * 65536 + t * 256 + c0 + j] = v;
        znT[(long)h * 65536 + (c0 + j) * 256 + t] = f2b(v);
    }
}

// ================= layernorm / softmax / misc =================================
__global__ __launch_bounds__(256) void layernorm_bf16(
    const float* __restrict__ x, const float* __restrict__ g,
    const float* __restrict__ b, u16* __restrict__ y) {
    __shared__ float sm[4];
    long base = (long)blockIdx.x * 512;
    int t = threadIdx.x;
    float v0 = x[base + t], v1 = x[base + 256 + t];
    float s = wred_sum(v0 + v1);
    if ((t & 63) == 0) sm[t >> 6] = s;
    __syncthreads();
    float mu = (sm[0] + sm[1] + sm[2] + sm[3]) * (1.f / 512.f);
    __syncthreads();
    float d0 = v0 - mu, d1 = v1 - mu;
    float q = wred_sum(d0 * d0 + d1 * d1);
    if ((t & 63) == 0) sm[t >> 6] = q;
    __syncthreads();
    float var = (sm[0] + sm[1] + sm[2] + sm[3]) * (1.f / 512.f);
    float rstd = rsqrtf(var + 1e-5f);
    y[base + t] = f2b(d0 * rstd * g[t] + b[t]);
    y[base + 256 + t] = f2b(d1 * rstd * g[256 + t] + b[256 + t]);
}

__global__ __launch_bounds__(256) void softmax_rows(float* __restrict__ data,
                                                    u16* __restrict__ outb, int ncols) {
    __shared__ float sm[4];
    float* row = data + (long)blockIdx.x * ncols;
    u16* rowb = outb + (long)blockIdx.x * ncols;
    int t = threadIdx.x;
    float m = -1e30f;
    for (int c = t; c < ncols; c += 256) m = fmaxf(m, row[c]);
    m = wred_max(m);
    if ((t & 63) == 0) sm[t >> 6] = m;
    __syncthreads();
    m = fmaxf(fmaxf(sm[0], sm[1]), fmaxf(sm[2], sm[3]));
    __syncthreads();
    float s = 0.f;
    for (int c = t; c < ncols; c += 256) {
        float e = __expf(row[c] - m);
        row[c] = e;
        s += e;
    }
    s = wred_sum(s);
    if ((t & 63) == 0) sm[t >> 6] = s;
    __syncthreads();
    s = sm[0] + sm[1] + sm[2] + sm[3];
    float inv = 1.f / s;
    for (int c = t; c < ncols; c += 256) {
        float v = row[c] * inv;
        row[c] = v;
        rowb[c] = f2b(v);
    }
}

__global__ void cls_copy(const float* __restrict__ cls, float* __restrict__ X) {
    X[threadIdx.x] = cls[threadIdx.x];
}
__global__ void build_hb(const float* __restrict__ h, u16* __restrict__ dst) {
    long idx = (long)blockIdx.x * 256 + threadIdx.x;
    long row = idx >> 10;
    int col = (int)(idx & 1023);
    float v = (row == 0) ? 0.f : h[((row - 1) << 10) + col];
    dst[idx] = f2b(v);
}
__global__ void transpose_to_bf16(const float* __restrict__ src, u16* __restrict__ dst,
                                  int R, int C) {
    long idx = (long)blockIdx.x * 256 + threadIdx.x;
    if (idx >= (long)R * C) return;
    int r = (int)(idx / C), c = (int)(idx % C);
    dst[(long)c * R + r] = f2b(src[idx]);
}
__global__ void landmarks_b(const u16* __restrict__ Qb, const u16* __restrict__ Kb,
                            u16* __restrict__ QLb, u16* __restrict__ KLb) {
    int h = blockIdx.x >> 8, j = blockIdx.x & 255, d = threadIdx.x;
    const u16* qb = Qb + ((long)h * 16384 + j * 64) * 64 + d;
    const u16* kb = Kb + ((long)h * 16384 + j * 64) * 64 + d;
    float sq = 0.f, sk = 0.f;
    for (int tk = 0; tk < 64; ++tk) {
        sq += b2f(qb[tk * 64]);
        sk += b2f(kb[tk * 64]);
    }
    QLb[((h << 8) + j) * 64 + d] = f2b(sq * (1.f / 64.f));
    KLb[((h << 8) + j) * 64 + d] = f2b(sk * (1.f / 64.f));
}
// per-head col/row abs-sum maxes -> maxes[2h], maxes[2h+1] (no atomics)
__global__ __launch_bounds__(256) void pinv_absmax(const float* __restrict__ a2,
                                                   float* __restrict__ maxes) {
    __shared__ float sm[8];
    const float* Xh = a2 + (long)blockIdx.x * 65536;
    int t = threadIdx.x;
    float cs = 0.f, rs = 0.f;
    for (int j = 0; j < 256; j++) {
        cs += fabsf(Xh[t * 256 + j]);
        rs += fabsf(Xh[j * 256 + t]);
    }
    float cm = wred_max(cs);
    if ((t & 63) == 0) sm[t >> 6] = cm;
    float rm = wred_max(rs);
    if ((t & 63) == 0) sm[4 + (t >> 6)] = rm;
    __syncthreads();
    if (t == 0) {
        maxes[blockIdx.x * 2] = fmaxf(fmaxf(sm[0], sm[1]), fmaxf(sm[2], sm[3]));
        maxes[blockIdx.x * 2 + 1] = fmaxf(fmaxf(sm[4], sm[5]), fmaxf(sm[6], sm[7]));
    }
}
__global__ void pinv_init(const float* __restrict__ a2, const float* __restrict__ maxes,
                          float* __restrict__ z, u16* __restrict__ zT) {
    long idx = (long)blockIdx.x * 256 + threadIdx.x;
    int h = (int)(idx >> 16);
    int rem = (int)(idx & 65535);
    int i = rem >> 8, j = rem & 255;
    float cm = maxes[0], rm = maxes[1];
#pragma unroll
    for (int k = 1; k < 8; k++) {
        cm = fmaxf(cm, maxes[2 * k]);
        rm = fmaxf(rm, maxes[2 * k + 1]);
    }
    float inv = 1.f / (cm * rm);
    float v = a2[((long)h << 16) + (j << 8) + i] * inv;
    z[idx] = v;
    zT[((long)h << 16) + (j << 8) + i] = f2b(v);
}
__global__ __launch_bounds__(256) void conv_kernel(const u16* __restrict__ VT,
                                                   const float* __restrict__ cw,
                                                   float* __restrict__ out) {
    int h = blockIdx.y;
    int n0 = blockIdx.x * 64;
    __shared__ float vt[64][97];
    int t = threadIdx.x;
    for (int i = t; i < 64 * 12; i += 256) {
        int d = i / 12, seg = i % 12;
        int n = n0 - 16 + seg * 8;
        const u16* src = VT + ((long)h * 64 + d) * 16384;
        if (n >= 0 && n + 8 <= 16384) {
            bf16x8 raw = *(const bf16x8*)(src + n);
#pragma unroll
            for (int j = 0; j < 8; j++)
                if (seg * 8 + j < 96) vt[d][seg * 8 + j] = b2f((u16)raw[j]);
        } else {
#pragma unroll
            for (int j = 0; j < 8; j++) {
                int nn = n + j;
                if (seg * 8 + j < 96)
                    vt[d][seg * 8 + j] = (nn >= 0 && nn < 16384) ? b2f(src[nn]) : 0.f;
            }
        }
    }
    __syncthreads();
    float w[33];
#pragma unroll
    for (int k = 0; k < 33; k++) w[k] = cw[h * 33 + k];
    int d = t & 63, ty = t >> 6;
    for (int nn = 0; nn < 16; nn++) {
        int nl = ty * 16 + nn;
        float s = 0.f;
#pragma unroll
        for (int k = 0; k < 33; k++) s += w[k] * vt[d][nl + k];
        out[((long)(n0 + nl)) * 512 + h * 64 + d] = s;
    }
}
__global__ void w2t_kernel(const float* __restrict__ W2, u16* __restrict__ W2T) {
    int idx = blockIdx.x * 256 + threadIdx.x;  // 8*256*64
    int h = idx >> 14, rem = idx & 16383, m = rem >> 6, d = rem & 63;
    W2T[(h << 14) + (d << 8) + m] = f2b(W2[idx]);
}
__global__ __launch_bounds__(256) void final_head(
    const float* __restrict__ X, const float* __restrict__ g, const float* __restrict__ b,
    const float* __restrict__ W, const float* __restrict__ bias, float* __restrict__ out) {
    __shared__ float sm[4];
    __shared__ float ln0[512];
    int t = threadIdx.x;
    float v0 = X[t], v1 = X[256 + t];
    float s = wred_sum(v0 + v1);
    if ((t & 63) == 0) sm[t >> 6] = s;
    __syncthreads();
    float mu = (sm[0] + sm[1] + sm[2] + sm[3]) * (1.f / 512.f);
    __syncthreads();
    float d0 = v0 - mu, d1 = v1 - mu;
    float q = wred_sum(d0 * d0 + d1 * d1);
    if ((t & 63) == 0) sm[t >> 6] = q;
    __syncthreads();
    float rstd = rsqrtf((sm[0] + sm[1] + sm[2] + sm[3]) * (1.f / 512.f) + 1e-5f);
    ln0[t] = d0 * rstd * g[t] + b[t];
    ln0[256 + t] = d1 * rstd * g[256 + t] + b[256 + t];
    __syncthreads();
    int jj = blockIdx.x * 256 + t;
    if (jj < 1000) {
        float acc = bias[jj];
        for (int dd = 0; dd < 512; ++dd) acc += ln0[dd] * W[dd * 1000 + jj];
        out[jj] = acc;
    }
}

// ================= layer driver ================================================
struct Bufs {
    float *X, *LNA, *A2, *Z0, *Z1, *XZ, *O, *W2, *MAXES, *PART;
    u16 *LNb, *Qb, *Kb, *VT, *QLb, *KLb, *W2T, *W1T, *QKVWT, *OUTWT;
    u16 *A2b, *ZT0, *ZT1;
};

static void run_layer(hipStream_t st, Bufs& B,
                      const float* ln_g, const float* ln_b, const float* qkv_W,
                      const float* conv_W, const float* out_W, const float* out_b) {
    const int N = 16384, D = 512, H = 8, DH = 64, M = 256;
    GP p{};
    // 1. LN -> bf16
    layernorm_bf16<<<N, 256, 0, st>>>(B.X, ln_g, ln_b, B.LNb);
    // 2. qkv: MODE-4 coalesced epilogue writes Q/K row-major + V^T directly
    transpose_to_bf16<<<(512 * 1536 + 255) / 256, 256, 0, st>>>(qkv_W, B.QKVWT, 512, 1536);
    p = GP{}; p.A = B.LNb; p.B = B.QKVWT; p.Q = B.Qb; p.Kb = B.Kb; p.V = B.VT; p.K = 512;
    launch_mgemm<128, 128, 4>(st, p, N, 1536, 1);
    // 3. landmarks
    landmarks_b<<<H * M, 64, 0, st>>>(B.Qb, B.Kb, B.QLb, B.KLb);
    // 4. sim2 -> softmax (fp32 + bf16 copy) -> pinv
    p = GP{}; p.A = B.QLb; p.B = B.KLb; p.C = B.A2; p.K = DH; p.ldc = M;
    p.sA = (long)M * DH; p.sB = (long)M * DH; p.sC = (long)M * M;
    launch_mgemm<128, 128, 0>(st, p, M, M, H);
    softmax_rows<<<H * M, 256, 0, st>>>(B.A2, B.A2b, M);
    pinv_absmax<<<H, 256, 0, st>>>(B.A2, B.MAXES);
    pinv_init<<<(H * M * M) / 256, 256, 0, st>>>(B.A2, B.MAXES, B.Z0, B.ZT0);
    float* z = B.Z0; float* zn = B.Z1;
    u16* zt = B.ZT0; u16* ztn = B.ZT1;
    for (int it = 0; it < 6; ++it) {
        p = GP{}; p.A = B.A2b; p.B = zt; p.C = B.XZ; p.K = M; p.ldc = M;
        p.sA = (long)M * M; p.sB = (long)M * M; p.sC = (long)M * M;
        launch_mgemm<128, 128, 0>(st, p, M, M, H);
        pinv_chain<<<dim3(32, 8), 256, 0, st>>>(B.XZ, z, zn, ztn);
        float* t1 = z; z = zn; zn = t1;
        u16* t2 = zt; zt = ztn; ztn = t2;
    }
    // 5. conv residual initializes ATTN (LNA)
    conv_kernel<<<dim3(N / 64, H), 256, 0, st>>>(B.VT, conv_W, B.LNA);
    // 6. fused sim3 flash (64 splits) + combine
    flash_a3v<<<dim3(64, 8), 256, 0, st>>>(B.QLb, B.Kb, B.VT, B.PART);
    a3v_combine<<<dim3(8, 4), 256, 0, st>>>(B.PART, B.O);
    // 7. W2 = z @ a3v (fp32), transpose to bf16
    gemm32(st, M, DH, M, z, M, (long)M * M, B.O, DH, (long)M * DH,
           B.W2, DH, (long)M * DH, H);
    w2t_kernel<<<512, 256, 0, st>>>(B.W2, B.W2T);
    // 8. fused sim1 -> softmax -> @W2 -> +conv -> LNb (bf16)
    attn1_fused<<<dim3(N / 64, H), 256, 0, st>>>(B.Qb, B.KLb, B.W2T, B.LNA, B.LNb);
    // 9. out projection: X += ATTN @ out_W + out_b
    transpose_to_bf16<<<(512 * 512 + 255) / 256, 256, 0, st>>>(out_W, B.OUTWT, 512, 512);
    p = GP{}; p.A = B.LNb; p.B = B.OUTWT; p.C = B.X; p.bias = out_b; p.K = D; p.ldc = D;
    launch_mgemm<128, 128, 2>(st, p, N, D, 1);
}

extern "C" void kernel_launch(void* const* d_in, const int* in_sizes, int n_in,
                              void* d_out, int out_size, void* d_ws, size_t ws_size,
                              hipStream_t stream) {
    const float* h_in = (const float*)d_in[0];
    const float* W1 = (const float*)d_in[1];
    const float* b1 = (const float*)d_in[2];
    const float* cls = (const float*)d_in[3];
    const float* ln1_g = (const float*)d_in[4];
    const float* ln1_b = (const float*)d_in[5];
    const float* qkv1_W = (const float*)d_in[6];
    const float* conv1_W = (const float*)d_in[7];
    const float* out1_W = (const float*)d_in[8];
    const float* out1_b = (const float*)d_in[9];
    const float* ln2_g = (const float*)d_in[10];
    const float* ln2_b = (const float*)d_in[11];
    const float* qkv2_W = (const float*)d_in[12];
    const float* conv2_W = (const float*)d_in[13];
    const float* out2_W = (const float*)d_in[14];
    const float* out2_b = (const float*)d_in[15];
    const float* lnf_g = (const float*)d_in[16];
    const float* lnf_b = (const float*)d_in[17];
    const float* fc2_W = (const float*)d_in[18];
    const float* fc2_b = (const float*)d_in[19];
    float* out = (float*)d_out;

    char* wsb = (char*)d_ws;
    size_t off = 0;
    auto alloc = [&](size_t bytes) -> void* {
        void* p = (void*)(wsb + off);
        off += (bytes + 255) & ~(size_t)255;
        return p;
    };
    Bufs B;
    B.X    = (float*)alloc((size_t)16384 * 512 * 4);
    B.LNA  = (float*)alloc((size_t)16384 * 512 * 4);
    B.LNb  = (u16*)alloc((size_t)16384 * 512 * 2);
    B.Qb   = (u16*)alloc((size_t)8 * 16384 * 64 * 2);   // adjacent to Kb: HB alias
    B.Kb   = (u16*)alloc((size_t)8 * 16384 * 64 * 2);
    B.VT   = (u16*)alloc((size_t)8 * 64 * 16384 * 2);
    B.QLb  = (u16*)alloc((size_t)8 * 256 * 64 * 2);
    B.KLb  = (u16*)alloc((size_t)8 * 256 * 64 * 2);
    B.A2   = (float*)alloc((size_t)8 * 256 * 256 * 4);
    B.A2b  = (u16*)alloc((size_t)8 * 256 * 256 * 2);
    B.Z0   = (float*)alloc((size_t)8 * 256 * 256 * 4);
    B.Z1   = (float*)alloc((size_t)8 * 256 * 256 * 4);
    B.ZT0  = (u16*)alloc((size_t)8 * 256 * 256 * 2);
    B.ZT1  = (u16*)alloc((size_t)8 * 256 * 256 * 2);
    B.XZ   = (float*)alloc((size_t)8 * 256 * 256 * 4);
    B.O    = (float*)alloc((size_t)8 * 256 * 64 * 4);
    B.W2   = (float*)alloc((size_t)8 * 256 * 64 * 4);
    B.W2T  = (u16*)alloc((size_t)8 * 64 * 256 * 2);
    B.W1T  = (u16*)alloc((size_t)512 * 1024 * 2);
    B.QKVWT = (u16*)alloc((size_t)1536 * 512 * 2);
    B.OUTWT = (u16*)alloc((size_t)512 * 512 * 2);
    B.MAXES = (float*)alloc(256);
    B.PART  = (float*)alloc((size_t)8 * 64 * 16896 * 4);
    if (off > ws_size) return;  // fail loudly (output stays poisoned)

    // fc1: HB (aliases Qb..Kb, 32MB) = [0; h] bf16; X = relu(HB @ W1^T + b1); X[0]=cls
    u16* HB = B.Qb;
    build_hb<<<(16384 * 1024) / 256, 256, 0, stream>>>(h_in, HB);
    transpose_to_bf16<<<(1024 * 512 + 255) / 256, 256, 0, stream>>>(W1, B.W1T, 1024, 512);
    {
        GP p{}; p.A = HB; p.B = B.W1T; p.C = B.X; p.bias = b1; p.K = 1024; p.ldc = 512;
        launch_mgemm<128, 128, 1>(stream, p, 16384, 512, 1);
    }
    cls_copy<<<1, 512, 0, stream>>>(cls, B.X);

    run_layer(stream, B, ln1_g, ln1_b, qkv1_W, conv1_W, out1_W, out1_b);
    run_layer(stream, B, ln2_g, ln2_b, qkv2_W, conv2_W, out2_W, out2_b);

    final_head<<<4, 256, 0, stream>>>(B.X, lnf_g, lnf_b, fc2_W, fc2_b, out);
}